// Round 1
// baseline (371.766 us; speedup 1.0000x reference)
//
#include <hip/hip_runtime.h>

typedef __attribute__((ext_vector_type(8))) short short8;
typedef __attribute__((ext_vector_type(8))) unsigned short u16x8;
typedef __attribute__((ext_vector_type(4))) float f32x4;

#define MFMA16 __builtin_amdgcn_mfma_f32_16x16x32_bf16

__device__ __forceinline__ unsigned short f2bf(float f) {
  unsigned int u = __builtin_bit_cast(unsigned int, f);
  u = (u + 0x7FFFu + ((u >> 16) & 1u)) >> 16;
  return (unsigned short)u;
}

// ---------------------------------------------------------------------------
// GEMM1: w[b,h,n,d] (bf16) = x[b*n, 512] @ w_qkv[512, 512]
// tile 128(M) x 64(N), BK=32, 4 waves (2x2), each wave 64x32
// ---------------------------------------------------------------------------
__global__ __launch_bounds__(256) void san_qkv(const float* __restrict__ x,
                                               const float* __restrict__ wqkv,
                                               unsigned short* __restrict__ w) {
  __shared__ unsigned short Alds[128 * 40];
  __shared__ unsigned short Blds[64 * 40];
  const int t = threadIdx.x;
  const int m0 = (blockIdx.x >> 3) * 128;
  const int n0 = (blockIdx.x & 7) * 64;
  const int lane = t & 63, wv = t >> 6;
  const int wr = wv >> 1, wc = wv & 1;
  const int lr = lane & 15, lg = lane >> 4;

  f32x4 acc[4][2];
  #pragma unroll
  for (int m = 0; m < 4; ++m)
    #pragma unroll
    for (int n = 0; n < 2; ++n) acc[m][n] = (f32x4){0.f, 0.f, 0.f, 0.f};

  for (int k0 = 0; k0 < 512; k0 += 32) {
    __syncthreads();
    {  // stage A: 128x32 fp32 -> bf16
      const int row = t >> 1, c0 = (t & 1) * 16;
      const float* src = x + (m0 + row) * 512 + k0 + c0;
      unsigned short tmp[16];
      #pragma unroll
      for (int i = 0; i < 4; ++i) {
        f32x4 v = *(const f32x4*)(src + i * 4);
        #pragma unroll
        for (int e = 0; e < 4; ++e) tmp[i * 4 + e] = f2bf(v[e]);
      }
      *(u16x8*)&Alds[row * 40 + c0]     = *(u16x8*)&tmp[0];
      *(u16x8*)&Alds[row * 40 + c0 + 8] = *(u16x8*)&tmp[8];
    }
    {  // stage B: 32x64 fp32 -> Bt[64][40] bf16 (transposed)
      const int k = t & 31, nb = (t >> 5) * 8;
      const float* src = wqkv + (k0 + k) * 512 + n0 + nb;
      #pragma unroll
      for (int i = 0; i < 8; i += 4) {
        f32x4 v = *(const f32x4*)(src + i);
        #pragma unroll
        for (int e = 0; e < 4; ++e) Blds[(nb + i + e) * 40 + k] = f2bf(v[e]);
      }
    }
    __syncthreads();
    short8 af[4], bfr[2];
    #pragma unroll
    for (int m = 0; m < 4; ++m)
      af[m] = *(const short8*)&Alds[(wr * 64 + m * 16 + lr) * 40 + lg * 8];
    #pragma unroll
    for (int n = 0; n < 2; ++n)
      bfr[n] = *(const short8*)&Blds[(wc * 32 + n * 16 + lr) * 40 + lg * 8];
    #pragma unroll
    for (int m = 0; m < 4; ++m)
      #pragma unroll
      for (int n = 0; n < 2; ++n)
        acc[m][n] = MFMA16(af[m], bfr[n], acc[m][n], 0, 0, 0);
  }
  // epilogue: C/D layout row=(lane>>4)*4+r, col=lane&15; write (b,h,n,d)
  #pragma unroll
  for (int m = 0; m < 4; ++m)
    #pragma unroll
    for (int n = 0; n < 2; ++n)
      #pragma unroll
      for (int r = 0; r < 4; ++r) {
        int grow = m0 + wr * 64 + m * 16 + lg * 4 + r;
        int gcol = n0 + wc * 32 + n * 16 + lr;
        int b = grow >> 12, nn = grow & 4095;
        int h = gcol >> 6, d = gcol & 63;
        w[((size_t)((b << 3) + h) * 4096 + nn) * 64 + d] = f2bf(acc[m][n][r]);
      }
}

// ---------------------------------------------------------------------------
// Flash attention, Q=K=V=w. One block = one (b,h) head x 64 q-rows.
// 4 waves x 16 q-rows each; KVBLK=64; K swizzled LDS, V transposed+swizzled.
// ---------------------------------------------------------------------------
__global__ __launch_bounds__(256) void san_attn(const unsigned short* __restrict__ w,
                                                unsigned short* __restrict__ o) {
  __shared__ unsigned short Klds[64 * 64];
  __shared__ unsigned short Vlds[64 * 64];
  __shared__ unsigned short Plds[4 * 16 * 72];
  const int t = threadIdx.x;
  const int lane = t & 63, wv = t >> 6;
  const int lr = lane & 15, lg = lane >> 4;
  const int bh = blockIdx.x >> 6;
  const int qt = blockIdx.x & 63;
  const unsigned short* wh = w + (size_t)bh * (4096 * 64);

  // Q fragments (A-operand): row = lane&15 of the wave's 16 q-rows
  const int qrow = qt * 64 + wv * 16 + lr;
  short8 qf[2];
  qf[0] = *(const short8*)(wh + qrow * 64 + lg * 8);
  qf[1] = *(const short8*)(wh + qrow * 64 + 32 + lg * 8);

  float mrow[4], lrow[4];
  f32x4 oacc[4];
  #pragma unroll
  for (int r = 0; r < 4; ++r) { mrow[r] = -__builtin_inff(); lrow[r] = 0.f; }
  #pragma unroll
  for (int dt = 0; dt < 4; ++dt) oacc[dt] = (f32x4){0.f, 0.f, 0.f, 0.f};

  const float cE = 0.125f * 1.4426950408889634f;  // scale * log2(e)

  for (int jt = 0; jt < 64; ++jt) {
    __syncthreads();
    const unsigned short* src = wh + jt * (64 * 64);
    // stage K: row-major [64][128B], XOR-swizzled
    #pragma unroll
    for (int i = 0; i < 2; ++i) {
      int c = t + i * 256;
      int row = c >> 3, off = (c & 7) * 16;
      u16x8 v = *(const u16x8*)(src + row * 64 + (off >> 1));
      *(u16x8*)((char*)Klds + row * 128 + (off ^ ((row & 7) << 4))) = v;
    }
    // stage V transposed: Vt[d][j], XOR-swizzled
    #pragma unroll
    for (int i = 0; i < 2; ++i) {
      int c = t + i * 256;
      int j = c >> 3, d0 = (c & 7) * 8;
      u16x8 v = *(const u16x8*)(src + j * 64 + d0);
      #pragma unroll
      for (int e = 0; e < 8; ++e) {
        int d = d0 + e;
        *(unsigned short*)((char*)Vlds + d * 128 + ((j * 2) ^ ((d & 7) << 4))) = v[e];
      }
    }
    __syncthreads();

    // S = Q K^T (raw; scale folded into exp2)
    f32x4 s[4];
    #pragma unroll
    for (int ct = 0; ct < 4; ++ct) {
      s[ct] = (f32x4){0.f, 0.f, 0.f, 0.f};
      #pragma unroll
      for (int kk = 0; kk < 2; ++kk) {
        int row = ct * 16 + lr;
        short8 kf = *(const short8*)((char*)Klds + row * 128 +
                                     ((kk * 64 + lg * 16) ^ ((row & 7) << 4)));
        s[ct] = MFMA16(qf[kk], kf, s[ct], 0, 0, 0);
      }
    }

    // online softmax (rows replicated across each 16-lane group)
    #pragma unroll
    for (int r = 0; r < 4; ++r) {
      float mx = fmaxf(fmaxf(s[0][r], s[1][r]), fmaxf(s[2][r], s[3][r]));
      #pragma unroll
      for (int off = 8; off; off >>= 1) mx = fmaxf(mx, __shfl_xor(mx, off));
      float mn = fmaxf(mrow[r], mx);
      float corr = exp2f((mrow[r] - mn) * cE);
      mrow[r] = mn;
      float psum = 0.f;
      #pragma unroll
      for (int ct = 0; ct < 4; ++ct) {
        float p = exp2f((s[ct][r] - mn) * cE);
        s[ct][r] = p;
        psum += p;
      }
      #pragma unroll
      for (int off = 8; off; off >>= 1) psum += __shfl_xor(psum, off);
      lrow[r] = lrow[r] * corr + psum;
      #pragma unroll
      for (int dt = 0; dt < 4; ++dt) oacc[dt][r] *= corr;
    }

    // P -> per-wave LDS tile [16][72] (padded: 2-way banks ~ free)
    char* pb = (char*)Plds + wv * 2304;
    #pragma unroll
    for (int ct = 0; ct < 4; ++ct)
      #pragma unroll
      for (int r = 0; r < 4; ++r)
        *(unsigned short*)(pb + (lg * 4 + r) * 144 + (ct * 16 + lr) * 2) =
            f2bf(s[ct][r]);

    // O += P @ V
    #pragma unroll
    for (int kk = 0; kk < 2; ++kk) {
      short8 pf = *(const short8*)(pb + lr * 144 + kk * 64 + lg * 16);
      #pragma unroll
      for (int dt = 0; dt < 4; ++dt) {
        int d = dt * 16 + lr;
        short8 vf = *(const short8*)((char*)Vlds + d * 128 +
                                     ((kk * 64 + lg * 16) ^ ((d & 7) << 4)));
        oacc[dt] = MFMA16(pf, vf, oacc[dt], 0, 0, 0);
      }
    }
  }

  // epilogue: normalize and store bf16 o in (b,h,n,d)
  unsigned short* oh = o + (size_t)bh * (4096 * 64);
  #pragma unroll
  for (int dt = 0; dt < 4; ++dt)
    #pragma unroll
    for (int r = 0; r < 4; ++r) {
      int row = qt * 64 + wv * 16 + lg * 4 + r;
      int d = dt * 16 + lr;
      oh[row * 64 + d] = f2bf(oacc[dt][r] / lrow[r]);
    }
}

// ---------------------------------------------------------------------------
// GEMM2: out[b*n, 512] (fp32) = o[(b,h,n,d)] @ w_out[512,512] + b_out
// ---------------------------------------------------------------------------
__global__ __launch_bounds__(256) void san_out(const unsigned short* __restrict__ o,
                                               const float* __restrict__ wo,
                                               const float* __restrict__ bias,
                                               float* __restrict__ out) {
  __shared__ unsigned short Alds[128 * 40];
  __shared__ unsigned short Blds[64 * 40];
  const int t = threadIdx.x;
  const int m0 = (blockIdx.x >> 3) * 128;
  const int n0 = (blockIdx.x & 7) * 64;
  const int lane = t & 63, wv = t >> 6;
  const int wr = wv >> 1, wc = wv & 1;
  const int lr = lane & 15, lg = lane >> 4;

  f32x4 acc[4][2];
  #pragma unroll
  for (int m = 0; m < 4; ++m)
    #pragma unroll
    for (int n = 0; n < 2; ++n) acc[m][n] = (f32x4){0.f, 0.f, 0.f, 0.f};

  for (int k0 = 0; k0 < 512; k0 += 32) {
    __syncthreads();
    {  // stage A from (b,h,n,d) bf16 buffer: k = h*64+d
      const int row = t >> 1, seg = t & 1;
      int grow = m0 + row;
      int b = grow >> 12, nn = grow & 4095;
      int h = k0 >> 6;
      int dbase = (k0 & 63) + seg * 16;
      const unsigned short* src =
          o + ((size_t)((b << 3) + h) * 4096 + nn) * 64 + dbase;
      *(u16x8*)&Alds[row * 40 + seg * 16]     = *(const u16x8*)src;
      *(u16x8*)&Alds[row * 40 + seg * 16 + 8] = *(const u16x8*)(src + 8);
    }
    {  // stage B: w_out 32x64 fp32 -> Bt[64][40] bf16
      const int k = t & 31, nb = (t >> 5) * 8;
      const float* src = wo + (k0 + k) * 512 + n0 + nb;
      #pragma unroll
      for (int i = 0; i < 8; i += 4) {
        f32x4 v = *(const f32x4*)(src + i);
        #pragma unroll
        for (int e = 0; e < 4; ++e) Blds[(nb + i + e) * 40 + k] = f2bf(v[e]);
      }
    }
    __syncthreads();
    short8 af[4], bfr[2];
    #pragma unroll
    for (int m = 0; m < 4; ++m)
      af[m] = *(const short8*)&Alds[(wr * 64 + m * 16 + lr) * 40 + lg * 8];
    #pragma unroll
    for (int n = 0; n < 2; ++n)
      bfr[n] = *(const short8*)&Blds[(wc * 32 + n * 16 + lr) * 40 + lg * 8];
    #pragma unroll
    for (int m = 0; m < 4; ++m)
      #pragma unroll
      for (int n = 0; n < 2; ++n)
        acc[m][n] = MFMA16(af[m], bfr[n], acc[m][n], 0, 0, 0);
  }
  #pragma unroll
  for (int m = 0; m < 4; ++m)
    #pragma unroll
    for (int n = 0; n < 2; ++n)
      #pragma unroll
      for (int r = 0; r < 4; ++r) {
        int grow = m0 + wr * 64 + m * 16 + lg * 4 + r;
        int gcol = n0 + wc * 32 + n * 16 + lr;
        out[(size_t)grow * 512 + gcol] = acc[m][n][r] + bias[gcol];
      }
}

extern "C" void kernel_launch(void* const* d_in, const int* in_sizes, int n_in,
                              void* d_out, int out_size, void* d_ws, size_t ws_size,
                              hipStream_t stream) {
  const float* x    = (const float*)d_in[0];
  const float* wqkv = (const float*)d_in[1];
  const float* wo   = (const float*)d_in[2];
  const float* bias = (const float*)d_in[3];
  float* out = (float*)d_out;

  unsigned short* wsw = (unsigned short*)d_ws;                       // 8 MB bf16 w
  unsigned short* wso = wsw + (size_t)2 * 8 * 4096 * 64;             // 8 MB bf16 o

  san_qkv<<<dim3(512), dim3(256), 0, stream>>>(x, wqkv, wsw);
  san_attn<<<dim3(1024), dim3(256), 0, stream>>>(wsw, wso);
  san_out<<<dim3(512), dim3(256), 0, stream>>>(wso, wo, bias, out);
}

// Round 2
// 180.450 us; speedup vs baseline: 2.0602x; 2.0602x over previous
//
#include <hip/hip_runtime.h>

typedef __attribute__((ext_vector_type(8))) short short8;
typedef __attribute__((ext_vector_type(8))) unsigned short u16x8;
typedef __attribute__((ext_vector_type(4))) float f32x4;
typedef __attribute__((ext_vector_type(16))) float f32x16;
typedef __attribute__((ext_vector_type(4))) unsigned int u32x4;

#define MFMA16 __builtin_amdgcn_mfma_f32_16x16x32_bf16
#define MFMA32 __builtin_amdgcn_mfma_f32_32x32x16_bf16

__device__ __forceinline__ unsigned short f2bf(float f) {
  unsigned int u = __builtin_bit_cast(unsigned int, f);
  u = (u + 0x7FFFu + ((u >> 16) & 1u)) >> 16;
  return (unsigned short)u;
}

__device__ __forceinline__ unsigned int cvt_pk_bf16(float lo, float hi) {
  unsigned int r;
  asm("v_cvt_pk_bf16_f32 %0, %1, %2" : "=v"(r) : "v"(lo), "v"(hi));
  return r;
}

__device__ __forceinline__ void pl32_swap(unsigned int& a, unsigned int& b) {
  asm("v_permlane32_swap_b32 %0, %1" : "+v"(a), "+v"(b));
}

#define GLOAD_LDS16(g, l)                                                   \
  __builtin_amdgcn_global_load_lds(                                         \
      (const __attribute__((address_space(1))) unsigned int*)(g),           \
      (__attribute__((address_space(3))) unsigned int*)(l), 16, 0, 0)

// ---------------------------------------------------------------------------
// GEMM1: w[b,h,n,d] and wT[b,h,d,n] (bf16) = x[b*n,512] @ w_qkv[512,512]
// ---------------------------------------------------------------------------
__global__ __launch_bounds__(256) void san_qkv(const float* __restrict__ x,
                                               const float* __restrict__ wqkv,
                                               unsigned short* __restrict__ w,
                                               unsigned short* __restrict__ wt) {
  __shared__ unsigned short Alds[128 * 40];
  __shared__ unsigned short Blds[64 * 40];
  const int t = threadIdx.x;
  const int m0 = (blockIdx.x >> 3) * 128;
  const int n0 = (blockIdx.x & 7) * 64;
  const int lane = t & 63, wv = t >> 6;
  const int wr = wv >> 1, wc = wv & 1;
  const int lr = lane & 15, lg = lane >> 4;

  f32x4 acc[4][2];
  #pragma unroll
  for (int m = 0; m < 4; ++m)
    #pragma unroll
    for (int n = 0; n < 2; ++n) acc[m][n] = (f32x4){0.f, 0.f, 0.f, 0.f};

  for (int k0 = 0; k0 < 512; k0 += 32) {
    __syncthreads();
    {  // stage A: 128x32 fp32 -> bf16
      const int row = t >> 1, c0 = (t & 1) * 16;
      const float* src = x + (m0 + row) * 512 + k0 + c0;
      unsigned short tmp[16];
      #pragma unroll
      for (int i = 0; i < 4; ++i) {
        f32x4 v = *(const f32x4*)(src + i * 4);
        #pragma unroll
        for (int e = 0; e < 4; ++e) tmp[i * 4 + e] = f2bf(v[e]);
      }
      *(u16x8*)&Alds[row * 40 + c0]     = *(u16x8*)&tmp[0];
      *(u16x8*)&Alds[row * 40 + c0 + 8] = *(u16x8*)&tmp[8];
    }
    {  // stage B: 32x64 fp32 -> Bt[64][40] bf16 (transposed)
      const int k = t & 31, nb = (t >> 5) * 8;
      const float* src = wqkv + (k0 + k) * 512 + n0 + nb;
      #pragma unroll
      for (int i = 0; i < 8; i += 4) {
        f32x4 v = *(const f32x4*)(src + i);
        #pragma unroll
        for (int e = 0; e < 4; ++e) Blds[(nb + i + e) * 40 + k] = f2bf(v[e]);
      }
    }
    __syncthreads();
    short8 af[4], bfr[2];
    #pragma unroll
    for (int m = 0; m < 4; ++m)
      af[m] = *(const short8*)&Alds[(wr * 64 + m * 16 + lr) * 40 + lg * 8];
    #pragma unroll
    for (int n = 0; n < 2; ++n)
      bfr[n] = *(const short8*)&Blds[(wc * 32 + n * 16 + lr) * 40 + lg * 8];
    #pragma unroll
    for (int m = 0; m < 4; ++m)
      #pragma unroll
      for (int n = 0; n < 2; ++n)
        acc[m][n] = MFMA16(af[m], bfr[n], acc[m][n], 0, 0, 0);
  }
  #pragma unroll
  for (int m = 0; m < 4; ++m)
    #pragma unroll
    for (int n = 0; n < 2; ++n) {
      int gcol = n0 + wc * 32 + n * 16 + lr;
      int h = gcol >> 6, d = gcol & 63;
      int grow0 = m0 + wr * 64 + m * 16 + lg * 4;
      int b = grow0 >> 12, nn0 = grow0 & 4095;
      size_t hb = (size_t)((b << 3) + h);
      #pragma unroll
      for (int r = 0; r < 4; ++r)
        w[(hb * 4096 + nn0 + r) * 64 + d] = f2bf(acc[m][n][r]);
      unsigned int p0 = cvt_pk_bf16(acc[m][n][0], acc[m][n][1]);
      unsigned int p1 = cvt_pk_bf16(acc[m][n][2], acc[m][n][3]);
      unsigned short* wtp = wt + ((hb << 6) + d) * 4096 + nn0;
      *(unsigned int*)(wtp)     = p0;
      *(unsigned int*)(wtp + 2) = p1;
    }
}

// ---------------------------------------------------------------------------
// Flash attention, Q=K=V=w, swapped-operand 32x32 MFMA.
// 256 blocks (16 bh x 16 q-blocks), 512 threads = 8 warps x 32 q-rows.
// K and V^T tiles (64 kv rows) double-buffered in LDS via global_load_lds
// with pre-swizzled source; P repacked in-register (cvt_pk + permlane32_swap).
// ---------------------------------------------------------------------------
__global__ __launch_bounds__(512, 2) void san_attn(
    const unsigned short* __restrict__ w, const unsigned short* __restrict__ wt,
    unsigned short* __restrict__ o) {
  __shared__ unsigned short Klds[2][4096];  // [64 j][64 d] swizzled
  __shared__ unsigned short Vlds[2][4096];  // [64 d][64 j] swizzled
  const int t = threadIdx.x;
  const int lane = t & 63, wp = t >> 6;
  const int lo5 = lane & 31, hi = lane >> 5;
  const int bh = blockIdx.x >> 4;
  const int qblk = blockIdx.x & 15;
  const unsigned short* wh = w + (size_t)bh * (4096 * 64);
  const unsigned short* wth = wt + (size_t)bh * (4096 * 64);

  // Q fragments (B operand): Q[q=lo5][d = s*16 + hi*8 + jj]
  const int qrow = qblk * 256 + wp * 32 + lo5;
  short8 qf0 = *(const short8*)(wh + qrow * 64 + 0 * 16 + hi * 8);
  short8 qf1 = *(const short8*)(wh + qrow * 64 + 1 * 16 + hi * 8);
  short8 qf2 = *(const short8*)(wh + qrow * 64 + 2 * 16 + hi * 8);
  short8 qf3 = *(const short8*)(wh + qrow * 64 + 3 * 16 + hi * 8);

  f32x16 oacc0, oacc1;
  #pragma unroll
  for (int r = 0; r < 16; ++r) { oacc0[r] = 0.f; oacc1[r] = 0.f; }
  float m_run = -1e30f, l_run = 0.f;
  const float cE = 0.125f * 1.4426950408889634f;

  // staging geometry: slot t -> row t>>3, 16B col ((t&7)*16) ^ swizzle
  const int srow = t >> 3;
  const int scol = ((t & 7) * 16) ^ ((srow & 7) << 4);

  auto stage = [&](int buf, int jt) {
    const char* ksrc = (const char*)wh + ((size_t)(jt * 64 + srow) << 7) + scol;
    const char* vsrc = (const char*)wth + ((size_t)srow << 13) + ((size_t)jt << 7) + scol;
    GLOAD_LDS16(ksrc, (char*)&Klds[buf][0] + t * 16);
    GLOAD_LDS16(vsrc, (char*)&Vlds[buf][0] + t * 16);
  };

  auto computeTile = [&](const unsigned short* kb, const unsigned short* vb) {
    // S^T = K · Q^T  (two 32x32 j-tiles)
    f32x16 st0, st1;
    #pragma unroll
    for (int r = 0; r < 16; ++r) { st0[r] = 0.f; st1[r] = 0.f; }
    {
      int j = lo5;
      #pragma unroll
      for (int s = 0; s < 4; ++s) {
        short8 kf = *(const short8*)((const char*)kb + j * 128 +
                                     ((s * 32 + hi * 16) ^ ((j & 7) << 4)));
        st0 = MFMA32(kf, (s == 0 ? qf0 : s == 1 ? qf1 : s == 2 ? qf2 : qf3), st0, 0, 0, 0);
      }
    }
    {
      int j = 32 + lo5;
      #pragma unroll
      for (int s = 0; s < 4; ++s) {
        short8 kf = *(const short8*)((const char*)kb + j * 128 +
                                     ((s * 32 + hi * 16) ^ ((j & 7) << 4)));
        st1 = MFMA32(kf, (s == 0 ? qf0 : s == 1 ? qf1 : s == 2 ? qf2 : qf3), st1, 0, 0, 0);
      }
    }

    // online softmax: lane owns row q=lo5 (32 of 64 j-values; partner has rest)
    float mx = st0[0];
    #pragma unroll
    for (int r = 1; r < 16; ++r) mx = fmaxf(mx, st0[r]);
    #pragma unroll
    for (int r = 0; r < 16; ++r) mx = fmaxf(mx, st1[r]);
    mx = fmaxf(mx, __shfl_xor(mx, 32));
    float mn = fmaxf(m_run, mx);
    float corr = exp2f((m_run - mn) * cE);
    m_run = mn;
    float mnc = mn * cE;
    float psum = 0.f;
    #pragma unroll
    for (int r = 0; r < 16; ++r) {
      float p = exp2f(st0[r] * cE - mnc);
      st0[r] = p; psum += p;
    }
    #pragma unroll
    for (int r = 0; r < 16; ++r) {
      float p = exp2f(st1[r] * cE - mnc);
      st1[r] = p; psum += p;
    }
    psum += __shfl_xor(psum, 32);
    l_run = l_run * corr + psum;
    #pragma unroll
    for (int r = 0; r < 16; ++r) { oacc0[r] *= corr; oacc1[r] *= corr; }

    // repack P -> bf16 B-operand fragments (cvt_pk + permlane32_swap)
    unsigned int c0 = cvt_pk_bf16(st0[0], st0[1]);
    unsigned int c1 = cvt_pk_bf16(st0[2], st0[3]);
    unsigned int c2 = cvt_pk_bf16(st0[4], st0[5]);
    unsigned int c3 = cvt_pk_bf16(st0[6], st0[7]);
    unsigned int c4 = cvt_pk_bf16(st0[8], st0[9]);
    unsigned int c5 = cvt_pk_bf16(st0[10], st0[11]);
    unsigned int c6 = cvt_pk_bf16(st0[12], st0[13]);
    unsigned int c7 = cvt_pk_bf16(st0[14], st0[15]);
    pl32_swap(c0, c2); pl32_swap(c1, c3);
    pl32_swap(c4, c6); pl32_swap(c5, c7);
    u32x4 u0 = {c0, c1, c2, c3}, u1 = {c4, c5, c6, c7};
    short8 pf0 = __builtin_bit_cast(short8, u0);
    short8 pf1 = __builtin_bit_cast(short8, u1);
    c0 = cvt_pk_bf16(st1[0], st1[1]);
    c1 = cvt_pk_bf16(st1[2], st1[3]);
    c2 = cvt_pk_bf16(st1[4], st1[5]);
    c3 = cvt_pk_bf16(st1[6], st1[7]);
    c4 = cvt_pk_bf16(st1[8], st1[9]);
    c5 = cvt_pk_bf16(st1[10], st1[11]);
    c6 = cvt_pk_bf16(st1[12], st1[13]);
    c7 = cvt_pk_bf16(st1[14], st1[15]);
    pl32_swap(c0, c2); pl32_swap(c1, c3);
    pl32_swap(c4, c6); pl32_swap(c5, c7);
    u32x4 u2 = {c0, c1, c2, c3}, u3 = {c4, c5, c6, c7};
    short8 pf2 = __builtin_bit_cast(short8, u2);
    short8 pf3 = __builtin_bit_cast(short8, u3);

    // O^T += V^T · P^T  (two 32-d tiles)
    {
      int d = lo5;
      #pragma unroll
      for (int s = 0; s < 4; ++s) {
        short8 vf = *(const short8*)((const char*)vb + d * 128 +
                                     ((s * 32 + hi * 16) ^ ((d & 7) << 4)));
        oacc0 = MFMA32(vf, (s == 0 ? pf0 : s == 1 ? pf1 : s == 2 ? pf2 : pf3), oacc0, 0, 0, 0);
      }
    }
    {
      int d = 32 + lo5;
      #pragma unroll
      for (int s = 0; s < 4; ++s) {
        short8 vf = *(const short8*)((const char*)vb + d * 128 +
                                     ((s * 32 + hi * 16) ^ ((d & 7) << 4)));
        oacc1 = MFMA32(vf, (s == 0 ? pf0 : s == 1 ? pf1 : s == 2 ? pf2 : pf3), oacc1, 0, 0, 0);
      }
    }
  };

  stage(0, 0);
  __syncthreads();
  for (int jt = 0; jt < 64; jt += 2) {
    stage(1, jt + 1);
    computeTile(&Klds[0][0], &Vlds[0][0]);
    __syncthreads();
    if (jt + 2 < 64) stage(0, jt + 2);
    computeTile(&Klds[1][0], &Vlds[1][0]);
    __syncthreads();
  }

  // epilogue: normalize, pack pairs, store o (b,h,n,d)
  float inv = 1.0f / l_run;
  unsigned short* oh = o + (size_t)bh * (4096 * 64);
  #pragma unroll
  for (int i = 0; i < 8; ++i) {
    unsigned int pk0 = cvt_pk_bf16(oacc0[2 * i] * inv, oacc0[2 * i + 1] * inv);
    unsigned int pk1 = cvt_pk_bf16(oacc1[2 * i] * inv, oacc1[2 * i + 1] * inv);
    int dl = ((2 * i) & 3) + 8 * ((2 * i) >> 2) + 4 * hi;
    *(unsigned int*)(oh + qrow * 64 + dl) = pk0;
    *(unsigned int*)(oh + qrow * 64 + 32 + dl) = pk1;
  }
}

// ---------------------------------------------------------------------------
// GEMM2: out[b*n,512] (fp32) = o[(b,h,n,d)] @ w_out[512,512] + b_out
// ---------------------------------------------------------------------------
__global__ __launch_bounds__(256) void san_out(const unsigned short* __restrict__ o,
                                               const float* __restrict__ wo,
                                               const float* __restrict__ bias,
                                               float* __restrict__ out) {
  __shared__ unsigned short Alds[128 * 40];
  __shared__ unsigned short Blds[64 * 40];
  const int t = threadIdx.x;
  const int m0 = (blockIdx.x >> 3) * 128;
  const int n0 = (blockIdx.x & 7) * 64;
  const int lane = t & 63, wv = t >> 6;
  const int wr = wv >> 1, wc = wv & 1;
  const int lr = lane & 15, lg = lane >> 4;

  f32x4 acc[4][2];
  #pragma unroll
  for (int m = 0; m < 4; ++m)
    #pragma unroll
    for (int n = 0; n < 2; ++n) acc[m][n] = (f32x4){0.f, 0.f, 0.f, 0.f};

  for (int k0 = 0; k0 < 512; k0 += 32) {
    __syncthreads();
    {
      const int row = t >> 1, seg = t & 1;
      int grow = m0 + row;
      int b = grow >> 12, nn = grow & 4095;
      int h = k0 >> 6;
      int dbase = (k0 & 63) + seg * 16;
      const unsigned short* src =
          o + ((size_t)((b << 3) + h) * 4096 + nn) * 64 + dbase;
      *(u16x8*)&Alds[row * 40 + seg * 16]     = *(const u16x8*)src;
      *(u16x8*)&Alds[row * 40 + seg * 16 + 8] = *(const u16x8*)(src + 8);
    }
    {
      const int k = t & 31, nb = (t >> 5) * 8;
      const float* src = wo + (k0 + k) * 512 + n0 + nb;
      #pragma unroll
      for (int i = 0; i < 8; i += 4) {
        f32x4 v = *(const f32x4*)(src + i);
        #pragma unroll
        for (int e = 0; e < 4; ++e) Blds[(nb + i + e) * 40 + k] = f2bf(v[e]);
      }
    }
    __syncthreads();
    short8 af[4], bfr[2];
    #pragma unroll
    for (int m = 0; m < 4; ++m)
      af[m] = *(const short8*)&Alds[(wr * 64 + m * 16 + lr) * 40 + lg * 8];
    #pragma unroll
    for (int n = 0; n < 2; ++n)
      bfr[n] = *(const short8*)&Blds[(wc * 32 + n * 16 + lr) * 40 + lg * 8];
    #pragma unroll
    for (int m = 0; m < 4; ++m)
      #pragma unroll
      for (int n = 0; n < 2; ++n)
        acc[m][n] = MFMA16(af[m], bfr[n], acc[m][n], 0, 0, 0);
  }
  #pragma unroll
  for (int m = 0; m < 4; ++m)
    #pragma unroll
    for (int n = 0; n < 2; ++n)
      #pragma unroll
      for (int r = 0; r < 4; ++r) {
        int grow = m0 + wr * 64 + m * 16 + lg * 4 + r;
        int gcol = n0 + wc * 32 + n * 16 + lr;
        out[(size_t)grow * 512 + gcol] = acc[m][n][r] + bias[gcol];
      }
}

extern "C" void kernel_launch(void* const* d_in, const int* in_sizes, int n_in,
                              void* d_out, int out_size, void* d_ws, size_t ws_size,
                              hipStream_t stream) {
  const float* x    = (const float*)d_in[0];
  const float* wqkv = (const float*)d_in[1];
  const float* wo   = (const float*)d_in[2];
  const float* bias = (const float*)d_in[3];
  float* out = (float*)d_out;

  unsigned short* wsw = (unsigned short*)d_ws;             // 8 MB bf16 w
  unsigned short* wso = wsw + (size_t)2 * 8 * 4096 * 64;   // 8 MB bf16 o
  unsigned short* wst = (unsigned short*)d_out;            // wT parked in d_out (16 MB fp32)

  san_qkv<<<dim3(512), dim3(256), 0, stream>>>(x, wqkv, wsw, wst);
  san_attn<<<dim3(256), dim3(512), 0, stream>>>(wsw, wst, wso);
  san_out<<<dim3(512), dim3(256), 0, stream>>>(wso, wo, bias, out);
}

// Round 4
// 171.380 us; speedup vs baseline: 2.1692x; 1.0529x over previous
//
#include <hip/hip_runtime.h>

typedef __attribute__((ext_vector_type(8))) short short8;
typedef __attribute__((ext_vector_type(8))) unsigned short u16x8;
typedef __attribute__((ext_vector_type(4))) float f32x4;
typedef __attribute__((ext_vector_type(16))) float f32x16;
typedef __attribute__((ext_vector_type(4))) unsigned int u32x4;

#define MFMA16 __builtin_amdgcn_mfma_f32_16x16x32_bf16
#define MFMA32 __builtin_amdgcn_mfma_f32_32x32x16_bf16

__device__ __forceinline__ unsigned short f2bf(float f) {
  unsigned int u = __builtin_bit_cast(unsigned int, f);
  u = (u + 0x7FFFu + ((u >> 16) & 1u)) >> 16;
  return (unsigned short)u;
}

__device__ __forceinline__ unsigned int cvt_pk_bf16(float lo, float hi) {
  unsigned int r;
  asm("v_cvt_pk_bf16_f32 %0, %1, %2" : "=v"(r) : "v"(lo), "v"(hi));
  return r;
}

__device__ __forceinline__ void pl32_swap(unsigned int& a, unsigned int& b) {
  asm("v_permlane32_swap_b32 %0, %1" : "+v"(a), "+v"(b));
}

#define GLOAD_LDS16(g, l)                                                   \
  __builtin_amdgcn_global_load_lds(                                         \
      (const __attribute__((address_space(1))) unsigned int*)(g),           \
      (__attribute__((address_space(3))) unsigned int*)(l), 16, 0, 0)

// ---------------------------------------------------------------------------
// GEMM1: w[b,h,n,d] and wT[b,h,d,n] (bf16) = x[b*n,512] @ w_qkv[512,512]
// ---------------------------------------------------------------------------
__global__ __launch_bounds__(256) void san_qkv(const float* __restrict__ x,
                                               const float* __restrict__ wqkv,
                                               unsigned short* __restrict__ w,
                                               unsigned short* __restrict__ wt) {
  __shared__ unsigned short Alds[128 * 40];
  __shared__ unsigned short Blds[64 * 40];
  const int t = threadIdx.x;
  const int m0 = (blockIdx.x >> 3) * 128;
  const int n0 = (blockIdx.x & 7) * 64;
  const int lane = t & 63, wv = t >> 6;
  const int wr = wv >> 1, wc = wv & 1;
  const int lr = lane & 15, lg = lane >> 4;

  f32x4 acc[4][2];
  #pragma unroll
  for (int m = 0; m < 4; ++m)
    #pragma unroll
    for (int n = 0; n < 2; ++n) acc[m][n] = (f32x4){0.f, 0.f, 0.f, 0.f};

  for (int k0 = 0; k0 < 512; k0 += 32) {
    __syncthreads();
    {  // stage A: 128x32 fp32 -> bf16
      const int row = t >> 1, c0 = (t & 1) * 16;
      const float* src = x + (m0 + row) * 512 + k0 + c0;
      unsigned short tmp[16];
      #pragma unroll
      for (int i = 0; i < 4; ++i) {
        f32x4 v = *(const f32x4*)(src + i * 4);
        #pragma unroll
        for (int e = 0; e < 4; ++e) tmp[i * 4 + e] = f2bf(v[e]);
      }
      *(u16x8*)&Alds[row * 40 + c0]     = *(u16x8*)&tmp[0];
      *(u16x8*)&Alds[row * 40 + c0 + 8] = *(u16x8*)&tmp[8];
    }
    {  // stage B: 32x64 fp32 -> Bt[64][40] bf16 (transposed)
      const int k = t & 31, nb = (t >> 5) * 8;
      const float* src = wqkv + (k0 + k) * 512 + n0 + nb;
      #pragma unroll
      for (int i = 0; i < 8; i += 4) {
        f32x4 v = *(const f32x4*)(src + i);
        #pragma unroll
        for (int e = 0; e < 4; ++e) Blds[(nb + i + e) * 40 + k] = f2bf(v[e]);
      }
    }
    __syncthreads();
    short8 af[4], bfr[2];
    #pragma unroll
    for (int m = 0; m < 4; ++m)
      af[m] = *(const short8*)&Alds[(wr * 64 + m * 16 + lr) * 40 + lg * 8];
    #pragma unroll
    for (int n = 0; n < 2; ++n)
      bfr[n] = *(const short8*)&Blds[(wc * 32 + n * 16 + lr) * 40 + lg * 8];
    #pragma unroll
    for (int m = 0; m < 4; ++m)
      #pragma unroll
      for (int n = 0; n < 2; ++n)
        acc[m][n] = MFMA16(af[m], bfr[n], acc[m][n], 0, 0, 0);
  }
  #pragma unroll
  for (int m = 0; m < 4; ++m)
    #pragma unroll
    for (int n = 0; n < 2; ++n) {
      int gcol = n0 + wc * 32 + n * 16 + lr;
      int h = gcol >> 6, d = gcol & 63;
      int grow0 = m0 + wr * 64 + m * 16 + lg * 4;
      int b = grow0 >> 12, nn0 = grow0 & 4095;
      size_t hb = (size_t)((b << 3) + h);
      #pragma unroll
      for (int r = 0; r < 4; ++r)
        w[(hb * 4096 + nn0 + r) * 64 + d] = f2bf(acc[m][n][r]);
      unsigned int p0 = cvt_pk_bf16(acc[m][n][0], acc[m][n][1]);
      unsigned int p1 = cvt_pk_bf16(acc[m][n][2], acc[m][n][3]);
      unsigned short* wtp = wt + ((hb << 6) + d) * 4096 + nn0;
      *(unsigned int*)(wtp)     = p0;
      *(unsigned int*)(wtp + 2) = p1;
    }
}

// ---------------------------------------------------------------------------
// Flash attention, Q=K=V=w, swapped-operand 32x32 MFMA.
// 512 blocks (16 bh x 32 q-blocks of 128 rows, XCD-local bh mapping),
// 256 threads = 4 waves x 32 q-rows. Per-tile compute is byte-identical to
// the round-2-verified version (shfl_xor softmax, unconditional rescale).
// ---------------------------------------------------------------------------
__global__ __launch_bounds__(256, 4) void san_attn(
    const unsigned short* __restrict__ w, const unsigned short* __restrict__ wt,
    unsigned short* __restrict__ o) {
  __shared__ unsigned short Klds[2][4096];  // [64 j][64 d] swizzled
  __shared__ unsigned short Vlds[2][4096];  // [64 d][64 j] swizzled
  const int t = threadIdx.x;
  const int lane = t & 63, wp = t >> 6;
  const int lo5 = lane & 31, hi = lane >> 5;
  const int bid = blockIdx.x;
  // XCD-local mapping: bh pair per XCD (bid%8 -> XCD on 8-XCD round-robin)
  const int bh = ((bid & 7) << 1) + ((bid >> 3) & 1);
  const int qblk = bid >> 4;  // 0..31, 128 q-rows each
  const unsigned short* wh = w + (size_t)bh * (4096 * 64);
  const unsigned short* wth = wt + (size_t)bh * (4096 * 64);

  // Q fragments (B operand): Q[q=lo5][d = s*16 + hi*8 + jj]
  const int qrow = qblk * 128 + wp * 32 + lo5;
  short8 qf0 = *(const short8*)(wh + qrow * 64 + 0 * 16 + hi * 8);
  short8 qf1 = *(const short8*)(wh + qrow * 64 + 1 * 16 + hi * 8);
  short8 qf2 = *(const short8*)(wh + qrow * 64 + 2 * 16 + hi * 8);
  short8 qf3 = *(const short8*)(wh + qrow * 64 + 3 * 16 + hi * 8);

  f32x16 oacc0, oacc1;
  #pragma unroll
  for (int r = 0; r < 16; ++r) { oacc0[r] = 0.f; oacc1[r] = 0.f; }
  float m_run = -1e30f, l_run = 0.f;
  const float cE = 0.125f * 1.4426950408889634f;

  auto stage = [&](int buf, int jt) {
    #pragma unroll
    for (int i = 0; i < 2; ++i) {
      int s = t + i * 256;
      int srow = s >> 3;
      int scol = ((s & 7) * 16) ^ ((srow & 7) << 4);
      const char* ksrc = (const char*)wh + ((size_t)(jt * 64 + srow) << 7) + scol;
      GLOAD_LDS16(ksrc, (char*)&Klds[buf][0] + s * 16);
      const char* vsrc = (const char*)wth + ((size_t)srow << 13) + ((size_t)jt << 7) + scol;
      GLOAD_LDS16(vsrc, (char*)&Vlds[buf][0] + s * 16);
    }
  };

  auto computeTile = [&](const unsigned short* kb, const unsigned short* vb) {
    // S^T = K · Q^T  (two 32x32 j-tiles)
    f32x16 st0, st1;
    #pragma unroll
    for (int r = 0; r < 16; ++r) { st0[r] = 0.f; st1[r] = 0.f; }
    __builtin_amdgcn_s_setprio(1);
    {
      int j = lo5;
      #pragma unroll
      for (int s = 0; s < 4; ++s) {
        short8 kf = *(const short8*)((const char*)kb + j * 128 +
                                     ((s * 32 + hi * 16) ^ ((j & 7) << 4)));
        st0 = MFMA32(kf, (s == 0 ? qf0 : s == 1 ? qf1 : s == 2 ? qf2 : qf3), st0, 0, 0, 0);
      }
    }
    {
      int j = 32 + lo5;
      #pragma unroll
      for (int s = 0; s < 4; ++s) {
        short8 kf = *(const short8*)((const char*)kb + j * 128 +
                                     ((s * 32 + hi * 16) ^ ((j & 7) << 4)));
        st1 = MFMA32(kf, (s == 0 ? qf0 : s == 1 ? qf1 : s == 2 ? qf2 : qf3), st1, 0, 0, 0);
      }
    }
    __builtin_amdgcn_s_setprio(0);

    // online softmax: lane owns row q=lo5 (32 of 64 j-values; partner has rest)
    float mx = st0[0];
    #pragma unroll
    for (int r = 1; r < 16; ++r) mx = fmaxf(mx, st0[r]);
    #pragma unroll
    for (int r = 0; r < 16; ++r) mx = fmaxf(mx, st1[r]);
    mx = fmaxf(mx, __shfl_xor(mx, 32));
    float mn = fmaxf(m_run, mx);
    float corr = exp2f((m_run - mn) * cE);
    m_run = mn;
    float mnc = mn * cE;
    float psum = 0.f;
    #pragma unroll
    for (int r = 0; r < 16; ++r) {
      float p = exp2f(st0[r] * cE - mnc);
      st0[r] = p; psum += p;
    }
    #pragma unroll
    for (int r = 0; r < 16; ++r) {
      float p = exp2f(st1[r] * cE - mnc);
      st1[r] = p; psum += p;
    }
    psum += __shfl_xor(psum, 32);
    l_run = l_run * corr + psum;
    #pragma unroll
    for (int r = 0; r < 16; ++r) { oacc0[r] *= corr; oacc1[r] *= corr; }

    // repack P -> bf16 B-operand fragments (cvt_pk + permlane32_swap)
    unsigned int c0 = cvt_pk_bf16(st0[0], st0[1]);
    unsigned int c1 = cvt_pk_bf16(st0[2], st0[3]);
    unsigned int c2 = cvt_pk_bf16(st0[4], st0[5]);
    unsigned int c3 = cvt_pk_bf16(st0[6], st0[7]);
    unsigned int c4 = cvt_pk_bf16(st0[8], st0[9]);
    unsigned int c5 = cvt_pk_bf16(st0[10], st0[11]);
    unsigned int c6 = cvt_pk_bf16(st0[12], st0[13]);
    unsigned int c7 = cvt_pk_bf16(st0[14], st0[15]);
    pl32_swap(c0, c2); pl32_swap(c1, c3);
    pl32_swap(c4, c6); pl32_swap(c5, c7);
    u32x4 u0 = {c0, c1, c2, c3}, u1 = {c4, c5, c6, c7};
    short8 pf0 = __builtin_bit_cast(short8, u0);
    short8 pf1 = __builtin_bit_cast(short8, u1);
    c0 = cvt_pk_bf16(st1[0], st1[1]);
    c1 = cvt_pk_bf16(st1[2], st1[3]);
    c2 = cvt_pk_bf16(st1[4], st1[5]);
    c3 = cvt_pk_bf16(st1[6], st1[7]);
    c4 = cvt_pk_bf16(st1[8], st1[9]);
    c5 = cvt_pk_bf16(st1[10], st1[11]);
    c6 = cvt_pk_bf16(st1[12], st1[13]);
    c7 = cvt_pk_bf16(st1[14], st1[15]);
    pl32_swap(c0, c2); pl32_swap(c1, c3);
    pl32_swap(c4, c6); pl32_swap(c5, c7);
    u32x4 u2 = {c0, c1, c2, c3}, u3 = {c4, c5, c6, c7};
    short8 pf2 = __builtin_bit_cast(short8, u2);
    short8 pf3 = __builtin_bit_cast(short8, u3);

    // O^T += V^T · P^T  (two 32-d tiles)
    __builtin_amdgcn_s_setprio(1);
    {
      int d = lo5;
      #pragma unroll
      for (int s = 0; s < 4; ++s) {
        short8 vf = *(const short8*)((const char*)vb + d * 128 +
                                     ((s * 32 + hi * 16) ^ ((d & 7) << 4)));
        oacc0 = MFMA32(vf, (s == 0 ? pf0 : s == 1 ? pf1 : s == 2 ? pf2 : pf3), oacc0, 0, 0, 0);
      }
    }
    {
      int d = 32 + lo5;
      #pragma unroll
      for (int s = 0; s < 4; ++s) {
        short8 vf = *(const short8*)((const char*)vb + d * 128 +
                                     ((s * 32 + hi * 16) ^ ((d & 7) << 4)));
        oacc1 = MFMA32(vf, (s == 0 ? pf0 : s == 1 ? pf1 : s == 2 ? pf2 : pf3), oacc1, 0, 0, 0);
      }
    }
    __builtin_amdgcn_s_setprio(0);
  };

  stage(0, 0);
  __syncthreads();
  for (int jt = 0; jt < 64; jt += 2) {
    stage(1, jt + 1);
    computeTile(&Klds[0][0], &Vlds[0][0]);
    __syncthreads();
    if (jt + 2 < 64) stage(0, jt + 2);
    computeTile(&Klds[1][0], &Vlds[1][0]);
    __syncthreads();
  }

  // epilogue: normalize, pack pairs, store o (b,h,n,d)
  float inv = 1.0f / l_run;
  unsigned short* oh = o + (size_t)bh * (4096 * 64);
  #pragma unroll
  for (int i = 0; i < 8; ++i) {
    unsigned int pk0 = cvt_pk_bf16(oacc0[2 * i] * inv, oacc0[2 * i + 1] * inv);
    unsigned int pk1 = cvt_pk_bf16(oacc1[2 * i] * inv, oacc1[2 * i + 1] * inv);
    int dl = ((2 * i) & 3) + 8 * ((2 * i) >> 2) + 4 * hi;
    *(unsigned int*)(oh + qrow * 64 + dl) = pk0;
    *(unsigned int*)(oh + qrow * 64 + 32 + dl) = pk1;
  }
}

// ---------------------------------------------------------------------------
// GEMM2: out[b*n,512] (fp32) = o[(b,h,n,d)] @ w_out[512,512] + b_out
// ---------------------------------------------------------------------------
__global__ __launch_bounds__(256) void san_out(const unsigned short* __restrict__ o,
                                               const float* __restrict__ wo,
                                               const float* __restrict__ bias,
                                               float* __restrict__ out) {
  __shared__ unsigned short Alds[128 * 40];
  __shared__ unsigned short Blds[64 * 40];
  const int t = threadIdx.x;
  const int m0 = (blockIdx.x >> 3) * 128;
  const int n0 = (blockIdx.x & 7) * 64;
  const int lane = t & 63, wv = t >> 6;
  const int wr = wv >> 1, wc = wv & 1;
  const int lr = lane & 15, lg = lane >> 4;

  f32x4 acc[4][2];
  #pragma unroll
  for (int m = 0; m < 4; ++m)
    #pragma unroll
    for (int n = 0; n < 2; ++n) acc[m][n] = (f32x4){0.f, 0.f, 0.f, 0.f};

  for (int k0 = 0; k0 < 512; k0 += 32) {
    __syncthreads();
    {
      const int row = t >> 1, seg = t & 1;
      int grow = m0 + row;
      int b = grow >> 12, nn = grow & 4095;
      int h = k0 >> 6;
      int dbase = (k0 & 63) + seg * 16;
      const unsigned short* src =
          o + ((size_t)((b << 3) + h) * 4096 + nn) * 64 + dbase;
      *(u16x8*)&Alds[row * 40 + seg * 16]     = *(const u16x8*)src;
      *(u16x8*)&Alds[row * 40 + seg * 16 + 8] = *(const u16x8*)(src + 8);
    }
    {
      const int k = t & 31, nb = (t >> 5) * 8;
      const float* src = wo + (k0 + k) * 512 + n0 + nb;
      #pragma unroll
      for (int i = 0; i < 8; i += 4) {
        f32x4 v = *(const f32x4*)(src + i);
        #pragma unroll
        for (int e = 0; e < 4; ++e) Blds[(nb + i + e) * 40 + k] = f2bf(v[e]);
      }
    }
    __syncthreads();
    short8 af[4], bfr[2];
    #pragma unroll
    for (int m = 0; m < 4; ++m)
      af[m] = *(const short8*)&Alds[(wr * 64 + m * 16 + lr) * 40 + lg * 8];
    #pragma unroll
    for (int n = 0; n < 2; ++n)
      bfr[n] = *(const short8*)&Blds[(wc * 32 + n * 16 + lr) * 40 + lg * 8];
    #pragma unroll
    for (int m = 0; m < 4; ++m)
      #pragma unroll
      for (int n = 0; n < 2; ++n)
        acc[m][n] = MFMA16(af[m], bfr[n], acc[m][n], 0, 0, 0);
  }
  #pragma unroll
  for (int m = 0; m < 4; ++m)
    #pragma unroll
    for (int n = 0; n < 2; ++n)
      #pragma unroll
      for (int r = 0; r < 4; ++r) {
        int grow = m0 + wr * 64 + m * 16 + lg * 4 + r;
        int gcol = n0 + wc * 32 + n * 16 + lr;
        out[(size_t)grow * 512 + gcol] = acc[m][n][r] + bias[gcol];
      }
}

extern "C" void kernel_launch(void* const* d_in, const int* in_sizes, int n_in,
                              void* d_out, int out_size, void* d_ws, size_t ws_size,
                              hipStream_t stream) {
  const float* x    = (const float*)d_in[0];
  const float* wqkv = (const float*)d_in[1];
  const float* wo   = (const float*)d_in[2];
  const float* bias = (const float*)d_in[3];
  float* out = (float*)d_out;

  unsigned short* wsw = (unsigned short*)d_ws;             // 8 MB bf16 w
  unsigned short* wso = wsw + (size_t)2 * 8 * 4096 * 64;   // 8 MB bf16 o
  unsigned short* wst = (unsigned short*)d_out;            // wT parked in d_out

  san_qkv<<<dim3(512), dim3(256), 0, stream>>>(x, wqkv, wsw, wst);
  san_attn<<<dim3(512), dim3(256), 0, stream>>>(wsw, wst, wso);
  san_out<<<dim3(512), dim3(256), 0, stream>>>(wso, wo, bias, out);
}

// Round 5
// 159.310 us; speedup vs baseline: 2.3336x; 1.0758x over previous
//
#include <hip/hip_runtime.h>

typedef __attribute__((ext_vector_type(8))) short short8;
typedef __attribute__((ext_vector_type(8))) unsigned short u16x8;
typedef __attribute__((ext_vector_type(4))) float f32x4;
typedef __attribute__((ext_vector_type(16))) float f32x16;
typedef __attribute__((ext_vector_type(4))) unsigned int u32x4;

#define MFMA16 __builtin_amdgcn_mfma_f32_16x16x32_bf16
#define MFMA32 __builtin_amdgcn_mfma_f32_32x32x16_bf16

__device__ __forceinline__ unsigned short f2bf(float f) {
  unsigned int u = __builtin_bit_cast(unsigned int, f);
  u = (u + 0x7FFFu + ((u >> 16) & 1u)) >> 16;
  return (unsigned short)u;
}

__device__ __forceinline__ unsigned int cvt_pk_bf16(float lo, float hi) {
  unsigned int r;
  asm("v_cvt_pk_bf16_f32 %0, %1, %2" : "=v"(r) : "v"(lo), "v"(hi));
  return r;
}

__device__ __forceinline__ void pl32_swap(unsigned int& a, unsigned int& b) {
  asm("v_permlane32_swap_b32 %0, %1" : "+v"(a), "+v"(b));
}

#define GLOAD_LDS16(g, l)                                                   \
  __builtin_amdgcn_global_load_lds(                                         \
      (const __attribute__((address_space(1))) unsigned int*)(g),           \
      (__attribute__((address_space(3))) unsigned int*)(l), 16, 0, 0)

// ---------------------------------------------------------------------------
// GEMM1: w[b,h,n,d] and wT[b,h,d,n] (bf16) = x[b*n,512] @ w_qkv[512,512]
// ---------------------------------------------------------------------------
__global__ __launch_bounds__(256) void san_qkv(const float* __restrict__ x,
                                               const float* __restrict__ wqkv,
                                               unsigned short* __restrict__ w,
                                               unsigned short* __restrict__ wt) {
  __shared__ unsigned short Alds[128 * 40];
  __shared__ unsigned short Blds[64 * 40];
  const int t = threadIdx.x;
  const int m0 = (blockIdx.x >> 3) * 128;
  const int n0 = (blockIdx.x & 7) * 64;
  const int lane = t & 63, wv = t >> 6;
  const int wr = wv >> 1, wc = wv & 1;
  const int lr = lane & 15, lg = lane >> 4;

  f32x4 acc[4][2];
  #pragma unroll
  for (int m = 0; m < 4; ++m)
    #pragma unroll
    for (int n = 0; n < 2; ++n) acc[m][n] = (f32x4){0.f, 0.f, 0.f, 0.f};

  for (int k0 = 0; k0 < 512; k0 += 32) {
    __syncthreads();
    {  // stage A: 128x32 fp32 -> bf16
      const int row = t >> 1, c0 = (t & 1) * 16;
      const float* src = x + (m0 + row) * 512 + k0 + c0;
      unsigned short tmp[16];
      #pragma unroll
      for (int i = 0; i < 4; ++i) {
        f32x4 v = *(const f32x4*)(src + i * 4);
        #pragma unroll
        for (int e = 0; e < 4; ++e) tmp[i * 4 + e] = f2bf(v[e]);
      }
      *(u16x8*)&Alds[row * 40 + c0]     = *(u16x8*)&tmp[0];
      *(u16x8*)&Alds[row * 40 + c0 + 8] = *(u16x8*)&tmp[8];
    }
    {  // stage B: 32x64 fp32 -> Bt[64][40] bf16 (transposed)
      const int k = t & 31, nb = (t >> 5) * 8;
      const float* src = wqkv + (k0 + k) * 512 + n0 + nb;
      #pragma unroll
      for (int i = 0; i < 8; i += 4) {
        f32x4 v = *(const f32x4*)(src + i);
        #pragma unroll
        for (int e = 0; e < 4; ++e) Blds[(nb + i + e) * 40 + k] = f2bf(v[e]);
      }
    }
    __syncthreads();
    short8 af[4], bfr[2];
    #pragma unroll
    for (int m = 0; m < 4; ++m)
      af[m] = *(const short8*)&Alds[(wr * 64 + m * 16 + lr) * 40 + lg * 8];
    #pragma unroll
    for (int n = 0; n < 2; ++n)
      bfr[n] = *(const short8*)&Blds[(wc * 32 + n * 16 + lr) * 40 + lg * 8];
    #pragma unroll
    for (int m = 0; m < 4; ++m)
      #pragma unroll
      for (int n = 0; n < 2; ++n)
        acc[m][n] = MFMA16(af[m], bfr[n], acc[m][n], 0, 0, 0);
  }
  #pragma unroll
  for (int m = 0; m < 4; ++m)
    #pragma unroll
    for (int n = 0; n < 2; ++n) {
      int gcol = n0 + wc * 32 + n * 16 + lr;
      int h = gcol >> 6, d = gcol & 63;
      int grow0 = m0 + wr * 64 + m * 16 + lg * 4;
      int b = grow0 >> 12, nn0 = grow0 & 4095;
      size_t hb = (size_t)((b << 3) + h);
      #pragma unroll
      for (int r = 0; r < 4; ++r)
        w[(hb * 4096 + nn0 + r) * 64 + d] = f2bf(acc[m][n][r]);
      unsigned int p0 = cvt_pk_bf16(acc[m][n][0], acc[m][n][1]);
      unsigned int p1 = cvt_pk_bf16(acc[m][n][2], acc[m][n][3]);
      unsigned short* wtp = wt + ((hb << 6) + d) * 4096 + nn0;
      *(unsigned int*)(wtp)     = p0;
      *(unsigned int*)(wtp + 2) = p1;
    }
}

// ---------------------------------------------------------------------------
// Flash attention, Q=K=V=w, swapped-operand 32x32 MFMA, kv-split-2.
// 512 blocks (16 bh x 32 q-blocks of 128 rows, XCD-local bh mapping),
// 512 threads = 8 waves: qgroup = wp&3 (32 q-rows), kvhalf = wp>>2
// (kv tiles 0-31 vs 32-63). Per-tile compute identical to the verified
// round-4 code; split states merged once through LDS at the end.
// ---------------------------------------------------------------------------
__global__ __launch_bounds__(512, 4) void san_attn(
    const unsigned short* __restrict__ w, const unsigned short* __restrict__ wt,
    unsigned short* __restrict__ o) {
  __shared__ char smem[65536];  // K: [buf][half] 8KB x4 ; V: +32768 same
  const int t = threadIdx.x;
  const int lane = t & 63, wp = t >> 6;
  const int lo5 = lane & 31, hi = lane >> 5;
  const int qg = wp & 3, kvhalf = wp >> 2;
  const int bid = blockIdx.x;
  const int bh = ((bid & 7) << 1) + ((bid >> 3) & 1);
  const int qblk = bid >> 4;  // 0..31, 128 q-rows each
  const unsigned short* wh = w + (size_t)bh * (4096 * 64);
  const unsigned short* wth = wt + (size_t)bh * (4096 * 64);

  // Q fragments (B operand): Q[q=lo5][d = s*16 + hi*8 + jj]
  const int qrow = qblk * 128 + qg * 32 + lo5;
  short8 qf0 = *(const short8*)(wh + qrow * 64 + 0 * 16 + hi * 8);
  short8 qf1 = *(const short8*)(wh + qrow * 64 + 1 * 16 + hi * 8);
  short8 qf2 = *(const short8*)(wh + qrow * 64 + 2 * 16 + hi * 8);
  short8 qf3 = *(const short8*)(wh + qrow * 64 + 3 * 16 + hi * 8);

  f32x16 oacc0, oacc1;
  #pragma unroll
  for (int r = 0; r < 16; ++r) { oacc0[r] = 0.f; oacc1[r] = 0.f; }
  float m_run = -1e30f, l_run = 0.f;
  const float cE = 0.125f * 1.4426950408889634f;

  // stage both halves' tiles: local tile index jt (0..31)
  const int srow = t >> 3;                                   // t in 0..511
  const int scol = ((t & 7) * 16) ^ ((srow & 7) << 4);
  auto stage = [&](int buf, int jt) {
    #pragma unroll
    for (int h = 0; h < 2; ++h) {
      int gt = h * 32 + jt;
      const char* ksrc = (const char*)wh + ((size_t)(gt * 64 + srow) << 7) + scol;
      GLOAD_LDS16(ksrc, smem + (buf * 2 + h) * 8192 + t * 16);
      const char* vsrc = (const char*)wth + ((size_t)srow << 13) + ((size_t)gt << 7) + scol;
      GLOAD_LDS16(vsrc, smem + 32768 + (buf * 2 + h) * 8192 + t * 16);
    }
  };

  auto computeTile = [&](const unsigned short* kb, const unsigned short* vb) {
    // S^T = K · Q^T  (two 32x32 j-tiles)
    f32x16 st0, st1;
    #pragma unroll
    for (int r = 0; r < 16; ++r) { st0[r] = 0.f; st1[r] = 0.f; }
    __builtin_amdgcn_s_setprio(1);
    {
      int j = lo5;
      #pragma unroll
      for (int s = 0; s < 4; ++s) {
        short8 kf = *(const short8*)((const char*)kb + j * 128 +
                                     ((s * 32 + hi * 16) ^ ((j & 7) << 4)));
        st0 = MFMA32(kf, (s == 0 ? qf0 : s == 1 ? qf1 : s == 2 ? qf2 : qf3), st0, 0, 0, 0);
      }
    }
    {
      int j = 32 + lo5;
      #pragma unroll
      for (int s = 0; s < 4; ++s) {
        short8 kf = *(const short8*)((const char*)kb + j * 128 +
                                     ((s * 32 + hi * 16) ^ ((j & 7) << 4)));
        st1 = MFMA32(kf, (s == 0 ? qf0 : s == 1 ? qf1 : s == 2 ? qf2 : qf3), st1, 0, 0, 0);
      }
    }
    __builtin_amdgcn_s_setprio(0);

    // online softmax: lane owns row q=lo5 (32 of 64 j-values; partner has rest)
    float mx = st0[0];
    #pragma unroll
    for (int r = 1; r < 16; ++r) mx = fmaxf(mx, st0[r]);
    #pragma unroll
    for (int r = 0; r < 16; ++r) mx = fmaxf(mx, st1[r]);
    mx = fmaxf(mx, __shfl_xor(mx, 32));
    float mn = fmaxf(m_run, mx);
    float corr = exp2f((m_run - mn) * cE);
    m_run = mn;
    float mnc = mn * cE;
    float psum = 0.f;
    #pragma unroll
    for (int r = 0; r < 16; ++r) {
      float p = exp2f(st0[r] * cE - mnc);
      st0[r] = p; psum += p;
    }
    #pragma unroll
    for (int r = 0; r < 16; ++r) {
      float p = exp2f(st1[r] * cE - mnc);
      st1[r] = p; psum += p;
    }
    psum += __shfl_xor(psum, 32);
    l_run = l_run * corr + psum;
    #pragma unroll
    for (int r = 0; r < 16; ++r) { oacc0[r] *= corr; oacc1[r] *= corr; }

    // repack P -> bf16 B-operand fragments (cvt_pk + permlane32_swap)
    unsigned int c0 = cvt_pk_bf16(st0[0], st0[1]);
    unsigned int c1 = cvt_pk_bf16(st0[2], st0[3]);
    unsigned int c2 = cvt_pk_bf16(st0[4], st0[5]);
    unsigned int c3 = cvt_pk_bf16(st0[6], st0[7]);
    unsigned int c4 = cvt_pk_bf16(st0[8], st0[9]);
    unsigned int c5 = cvt_pk_bf16(st0[10], st0[11]);
    unsigned int c6 = cvt_pk_bf16(st0[12], st0[13]);
    unsigned int c7 = cvt_pk_bf16(st0[14], st0[15]);
    pl32_swap(c0, c2); pl32_swap(c1, c3);
    pl32_swap(c4, c6); pl32_swap(c5, c7);
    u32x4 u0 = {c0, c1, c2, c3}, u1 = {c4, c5, c6, c7};
    short8 pf0 = __builtin_bit_cast(short8, u0);
    short8 pf1 = __builtin_bit_cast(short8, u1);
    c0 = cvt_pk_bf16(st1[0], st1[1]);
    c1 = cvt_pk_bf16(st1[2], st1[3]);
    c2 = cvt_pk_bf16(st1[4], st1[5]);
    c3 = cvt_pk_bf16(st1[6], st1[7]);
    c4 = cvt_pk_bf16(st1[8], st1[9]);
    c5 = cvt_pk_bf16(st1[10], st1[11]);
    c6 = cvt_pk_bf16(st1[12], st1[13]);
    c7 = cvt_pk_bf16(st1[14], st1[15]);
    pl32_swap(c0, c2); pl32_swap(c1, c3);
    pl32_swap(c4, c6); pl32_swap(c5, c7);
    u32x4 u2 = {c0, c1, c2, c3}, u3 = {c4, c5, c6, c7};
    short8 pf2 = __builtin_bit_cast(short8, u2);
    short8 pf3 = __builtin_bit_cast(short8, u3);

    // O^T += V^T · P^T  (two 32-d tiles)
    __builtin_amdgcn_s_setprio(1);
    {
      int d = lo5;
      #pragma unroll
      for (int s = 0; s < 4; ++s) {
        short8 vf = *(const short8*)((const char*)vb + d * 128 +
                                     ((s * 32 + hi * 16) ^ ((d & 7) << 4)));
        oacc0 = MFMA32(vf, (s == 0 ? pf0 : s == 1 ? pf1 : s == 2 ? pf2 : pf3), oacc0, 0, 0, 0);
      }
    }
    {
      int d = 32 + lo5;
      #pragma unroll
      for (int s = 0; s < 4; ++s) {
        short8 vf = *(const short8*)((const char*)vb + d * 128 +
                                     ((s * 32 + hi * 16) ^ ((d & 7) << 4)));
        oacc1 = MFMA32(vf, (s == 0 ? pf0 : s == 1 ? pf1 : s == 2 ? pf2 : pf3), oacc1, 0, 0, 0);
      }
    }
    __builtin_amdgcn_s_setprio(0);
  };

  auto kbuf = [&](int buf) {
    return (const unsigned short*)(smem + (buf * 2 + kvhalf) * 8192);
  };
  auto vbuf = [&](int buf) {
    return (const unsigned short*)(smem + 32768 + (buf * 2 + kvhalf) * 8192);
  };

  stage(0, 0);
  __syncthreads();
  for (int jt = 0; jt < 32; jt += 2) {
    stage(1, jt + 1);
    computeTile(kbuf(0), vbuf(0));
    __syncthreads();
    if (jt + 2 < 32) stage(0, jt + 2);
    computeTile(kbuf(1), vbuf(1));
    __syncthreads();
  }

  // merge the two kv-half states (per q-group pair: wave qg <-> wave qg+4)
  float* scratch = (float*)smem;
  float* obase = scratch + qg * 2176;  // 8 chunks*256 + 64 m + 64 l floats
  if (kvhalf == 1) {
    #pragma unroll
    for (int c = 0; c < 4; ++c) {
      f32x4 v = {oacc0[4 * c], oacc0[4 * c + 1], oacc0[4 * c + 2], oacc0[4 * c + 3]};
      *(f32x4*)(obase + c * 256 + lane * 4) = v;
    }
    #pragma unroll
    for (int c = 0; c < 4; ++c) {
      f32x4 v = {oacc1[4 * c], oacc1[4 * c + 1], oacc1[4 * c + 2], oacc1[4 * c + 3]};
      *(f32x4*)(obase + 1024 + c * 256 + lane * 4) = v;
    }
    obase[2048 + lane] = m_run;
    obase[2112 + lane] = l_run;
  }
  __syncthreads();
  if (kvhalf == 0) {
    float m_b = obase[2048 + lane];
    float l_b = obase[2112 + lane];
    float mn = fmaxf(m_run, m_b);
    float ca = exp2f((m_run - mn) * cE);
    float cb = exp2f((m_b - mn) * cE);
    float linv = 1.f / (l_run * ca + l_b * cb);
    float ob0[16], ob1[16];
    #pragma unroll
    for (int c = 0; c < 4; ++c) {
      f32x4 v = *(const f32x4*)(obase + c * 256 + lane * 4);
      #pragma unroll
      for (int e = 0; e < 4; ++e) ob0[4 * c + e] = v[e];
    }
    #pragma unroll
    for (int c = 0; c < 4; ++c) {
      f32x4 v = *(const f32x4*)(obase + 1024 + c * 256 + lane * 4);
      #pragma unroll
      for (int e = 0; e < 4; ++e) ob1[4 * c + e] = v[e];
    }
    unsigned short* oh = o + (size_t)bh * (4096 * 64);
    #pragma unroll
    for (int i = 0; i < 8; ++i) {
      float a0 = (oacc0[2 * i] * ca + ob0[2 * i] * cb) * linv;
      float a1 = (oacc0[2 * i + 1] * ca + ob0[2 * i + 1] * cb) * linv;
      float b0 = (oacc1[2 * i] * ca + ob1[2 * i] * cb) * linv;
      float b1 = (oacc1[2 * i + 1] * ca + ob1[2 * i + 1] * cb) * linv;
      unsigned int pk0 = cvt_pk_bf16(a0, a1);
      unsigned int pk1 = cvt_pk_bf16(b0, b1);
      int dl = ((2 * i) & 3) + 8 * ((2 * i) >> 2) + 4 * hi;
      *(unsigned int*)(oh + qrow * 64 + dl) = pk0;
      *(unsigned int*)(oh + qrow * 64 + 32 + dl) = pk1;
    }
  }
}

// ---------------------------------------------------------------------------
// GEMM2: out[b*n,512] (fp32) = o[(b,h,n,d)] @ w_out[512,512] + b_out
// ---------------------------------------------------------------------------
__global__ __launch_bounds__(256) void san_out(const unsigned short* __restrict__ o,
                                               const float* __restrict__ wo,
                                               const float* __restrict__ bias,
                                               float* __restrict__ out) {
  __shared__ unsigned short Alds[128 * 40];
  __shared__ unsigned short Blds[64 * 40];
  const int t = threadIdx.x;
  const int m0 = (blockIdx.x >> 3) * 128;
  const int n0 = (blockIdx.x & 7) * 64;
  const int lane = t & 63, wv = t >> 6;
  const int wr = wv >> 1, wc = wv & 1;
  const int lr = lane & 15, lg = lane >> 4;

  f32x4 acc[4][2];
  #pragma unroll
  for (int m = 0; m < 4; ++m)
    #pragma unroll
    for (int n = 0; n < 2; ++n) acc[m][n] = (f32x4){0.f, 0.f, 0.f, 0.f};

  for (int k0 = 0; k0 < 512; k0 += 32) {
    __syncthreads();
    {
      const int row = t >> 1, seg = t & 1;
      int grow = m0 + row;
      int b = grow >> 12, nn = grow & 4095;
      int h = k0 >> 6;
      int dbase = (k0 & 63) + seg * 16;
      const unsigned short* src =
          o + ((size_t)((b << 3) + h) * 4096 + nn) * 64 + dbase;
      *(u16x8*)&Alds[row * 40 + seg * 16]     = *(const u16x8*)src;
      *(u16x8*)&Alds[row * 40 + seg * 16 + 8] = *(const u16x8*)(src + 8);
    }
    {
      const int k = t & 31, nb = (t >> 5) * 8;
      const float* src = wo + (k0 + k) * 512 + n0 + nb;
      #pragma unroll
      for (int i = 0; i < 8; i += 4) {
        f32x4 v = *(const f32x4*)(src + i);
        #pragma unroll
        for (int e = 0; e < 4; ++e) Blds[(nb + i + e) * 40 + k] = f2bf(v[e]);
      }
    }
    __syncthreads();
    short8 af[4], bfr[2];
    #pragma unroll
    for (int m = 0; m < 4; ++m)
      af[m] = *(const short8*)&Alds[(wr * 64 + m * 16 + lr) * 40 + lg * 8];
    #pragma unroll
    for (int n = 0; n < 2; ++n)
      bfr[n] = *(const short8*)&Blds[(wc * 32 + n * 16 + lr) * 40 + lg * 8];
    #pragma unroll
    for (int m = 0; m < 4; ++m)
      #pragma unroll
      for (int n = 0; n < 2; ++n)
        acc[m][n] = MFMA16(af[m], bfr[n], acc[m][n], 0, 0, 0);
  }
  #pragma unroll
  for (int m = 0; m < 4; ++m)
    #pragma unroll
    for (int n = 0; n < 2; ++n)
      #pragma unroll
      for (int r = 0; r < 4; ++r) {
        int grow = m0 + wr * 64 + m * 16 + lg * 4 + r;
        int gcol = n0 + wc * 32 + n * 16 + lr;
        out[(size_t)grow * 512 + gcol] = acc[m][n][r] + bias[gcol];
      }
}

extern "C" void kernel_launch(void* const* d_in, const int* in_sizes, int n_in,
                              void* d_out, int out_size, void* d_ws, size_t ws_size,
                              hipStream_t stream) {
  const float* x    = (const float*)d_in[0];
  const float* wqkv = (const float*)d_in[1];
  const float* wo   = (const float*)d_in[2];
  const float* bias = (const float*)d_in[3];
  float* out = (float*)d_out;

  unsigned short* wsw = (unsigned short*)d_ws;             // 8 MB bf16 w
  unsigned short* wso = wsw + (size_t)2 * 8 * 4096 * 64;   // 8 MB bf16 o
  unsigned short* wst = (unsigned short*)d_out;            // wT parked in d_out

  san_qkv<<<dim3(512), dim3(256), 0, stream>>>(x, wqkv, wsw, wst);
  san_attn<<<dim3(512), dim3(512), 0, stream>>>(wsw, wst, wso);
  san_out<<<dim3(512), dim3(256), 0, stream>>>(wso, wo, bias, out);
}

// Round 6
// 148.895 us; speedup vs baseline: 2.4968x; 1.0699x over previous
//
#include <hip/hip_runtime.h>

typedef __attribute__((ext_vector_type(8))) short short8;
typedef __attribute__((ext_vector_type(8))) unsigned short u16x8;
typedef __attribute__((ext_vector_type(4))) float f32x4;
typedef __attribute__((ext_vector_type(16))) float f32x16;
typedef __attribute__((ext_vector_type(4))) unsigned int u32x4;

#define MFMA16 __builtin_amdgcn_mfma_f32_16x16x32_bf16
#define MFMA32 __builtin_amdgcn_mfma_f32_32x32x16_bf16

__device__ __forceinline__ unsigned short f2bf(float f) {
  unsigned int u = __builtin_bit_cast(unsigned int, f);
  u = (u + 0x7FFFu + ((u >> 16) & 1u)) >> 16;
  return (unsigned short)u;
}

__device__ __forceinline__ unsigned int cvt_pk_bf16(float lo, float hi) {
  unsigned int r;
  asm("v_cvt_pk_bf16_f32 %0, %1, %2" : "=v"(r) : "v"(lo), "v"(hi));
  return r;
}

__device__ __forceinline__ void pl32_swap(unsigned int& a, unsigned int& b) {
  asm("v_permlane32_swap_b32 %0, %1" : "+v"(a), "+v"(b));
}

#define GLOAD_LDS16(g, l)                                                   \
  __builtin_amdgcn_global_load_lds(                                         \
      (const __attribute__((address_space(1))) unsigned int*)(g),           \
      (__attribute__((address_space(3))) unsigned int*)(l), 16, 0, 0)

// ---------------------------------------------------------------------------
// GEMM1: w[b,h,n,d] and wT[b,h,d,n] (bf16) = x[b*n,512] @ w_qkv[512,512]
// ---------------------------------------------------------------------------
__global__ __launch_bounds__(256) void san_qkv(const float* __restrict__ x,
                                               const float* __restrict__ wqkv,
                                               unsigned short* __restrict__ w,
                                               unsigned short* __restrict__ wt) {
  __shared__ unsigned short Alds[128 * 40];
  __shared__ unsigned short Blds[64 * 40];
  const int t = threadIdx.x;
  const int m0 = (blockIdx.x >> 3) * 128;
  const int n0 = (blockIdx.x & 7) * 64;
  const int lane = t & 63, wv = t >> 6;
  const int wr = wv >> 1, wc = wv & 1;
  const int lr = lane & 15, lg = lane >> 4;

  f32x4 acc[4][2];
  #pragma unroll
  for (int m = 0; m < 4; ++m)
    #pragma unroll
    for (int n = 0; n < 2; ++n) acc[m][n] = (f32x4){0.f, 0.f, 0.f, 0.f};

  for (int k0 = 0; k0 < 512; k0 += 32) {
    __syncthreads();
    {  // stage A: 128x32 fp32 -> bf16
      const int row = t >> 1, c0 = (t & 1) * 16;
      const float* src = x + (m0 + row) * 512 + k0 + c0;
      unsigned short tmp[16];
      #pragma unroll
      for (int i = 0; i < 4; ++i) {
        f32x4 v = *(const f32x4*)(src + i * 4);
        #pragma unroll
        for (int e = 0; e < 4; ++e) tmp[i * 4 + e] = f2bf(v[e]);
      }
      *(u16x8*)&Alds[row * 40 + c0]     = *(u16x8*)&tmp[0];
      *(u16x8*)&Alds[row * 40 + c0 + 8] = *(u16x8*)&tmp[8];
    }
    {  // stage B: 32x64 fp32 -> Bt[64][40] bf16 (transposed)
      const int k = t & 31, nb = (t >> 5) * 8;
      const float* src = wqkv + (k0 + k) * 512 + n0 + nb;
      #pragma unroll
      for (int i = 0; i < 8; i += 4) {
        f32x4 v = *(const f32x4*)(src + i);
        #pragma unroll
        for (int e = 0; e < 4; ++e) Blds[(nb + i + e) * 40 + k] = f2bf(v[e]);
      }
    }
    __syncthreads();
    short8 af[4], bfr[2];
    #pragma unroll
    for (int m = 0; m < 4; ++m)
      af[m] = *(const short8*)&Alds[(wr * 64 + m * 16 + lr) * 40 + lg * 8];
    #pragma unroll
    for (int n = 0; n < 2; ++n)
      bfr[n] = *(const short8*)&Blds[(wc * 32 + n * 16 + lr) * 40 + lg * 8];
    #pragma unroll
    for (int m = 0; m < 4; ++m)
      #pragma unroll
      for (int n = 0; n < 2; ++n)
        acc[m][n] = MFMA16(af[m], bfr[n], acc[m][n], 0, 0, 0);
  }
  #pragma unroll
  for (int m = 0; m < 4; ++m)
    #pragma unroll
    for (int n = 0; n < 2; ++n) {
      int gcol = n0 + wc * 32 + n * 16 + lr;
      int h = gcol >> 6, d = gcol & 63;
      int grow0 = m0 + wr * 64 + m * 16 + lg * 4;
      int b = grow0 >> 12, nn0 = grow0 & 4095;
      size_t hb = (size_t)((b << 3) + h);
      #pragma unroll
      for (int r = 0; r < 4; ++r)
        w[(hb * 4096 + nn0 + r) * 64 + d] = f2bf(acc[m][n][r]);
      unsigned int p0 = cvt_pk_bf16(acc[m][n][0], acc[m][n][1]);
      unsigned int p1 = cvt_pk_bf16(acc[m][n][2], acc[m][n][3]);
      unsigned short* wtp = wt + ((hb << 6) + d) * 4096 + nn0;
      *(unsigned int*)(wtp)     = p0;
      *(unsigned int*)(wtp + 2) = p1;
    }
}

// ---------------------------------------------------------------------------
// Flash attention, Q=K=V=w, swapped-operand 32x32 MFMA, kv-split-2.
// Static-shift softmax: p = exp2(S*cE - M*cE), M=160 raw-S units (safe upper
// bound; softmax is shift-invariant so result is mathematically identical).
// No per-tile max reduce / rescale / cross-lane ops; l combined once at end.
// ---------------------------------------------------------------------------
__global__ __launch_bounds__(512, 4) void san_attn(
    const unsigned short* __restrict__ w, const unsigned short* __restrict__ wt,
    unsigned short* __restrict__ o) {
  __shared__ char smem[65536];  // K: [buf][half] 8KB x4 ; V: +32768 same
  const int t = threadIdx.x;
  const int lane = t & 63, wp = t >> 6;
  const int lo5 = lane & 31, hi = lane >> 5;
  const int qg = wp & 3, kvhalf = wp >> 2;
  const int bid = blockIdx.x;
  const int bh = ((bid & 7) << 1) + ((bid >> 3) & 1);
  const int qblk = bid >> 4;  // 0..31, 128 q-rows each
  const unsigned short* wh = w + (size_t)bh * (4096 * 64);
  const unsigned short* wth = wt + (size_t)bh * (4096 * 64);

  // Q fragments (B operand): Q[q=lo5][d = s*16 + hi*8 + jj]
  const int qrow = qblk * 128 + qg * 32 + lo5;
  short8 qf0 = *(const short8*)(wh + qrow * 64 + 0 * 16 + hi * 8);
  short8 qf1 = *(const short8*)(wh + qrow * 64 + 1 * 16 + hi * 8);
  short8 qf2 = *(const short8*)(wh + qrow * 64 + 2 * 16 + hi * 8);
  short8 qf3 = *(const short8*)(wh + qrow * 64 + 3 * 16 + hi * 8);

  f32x16 oacc0, oacc1;
  #pragma unroll
  for (int r = 0; r < 16; ++r) { oacc0[r] = 0.f; oacc1[r] = 0.f; }
  float l_run = 0.f;
  const float cE = 0.125f * 1.4426950408889634f;
  const float mnc = 28.8539008178f;  // 160 * cE

  // stage both halves' tiles: local tile index jt (0..31)
  const int srow = t >> 3;                                   // t in 0..511
  const int scol = ((t & 7) * 16) ^ ((srow & 7) << 4);
  auto stage = [&](int buf, int jt) {
    #pragma unroll
    for (int h = 0; h < 2; ++h) {
      int gt = h * 32 + jt;
      const char* ksrc = (const char*)wh + ((size_t)(gt * 64 + srow) << 7) + scol;
      GLOAD_LDS16(ksrc, smem + (buf * 2 + h) * 8192 + t * 16);
      const char* vsrc = (const char*)wth + ((size_t)srow << 13) + ((size_t)gt << 7) + scol;
      GLOAD_LDS16(vsrc, smem + 32768 + (buf * 2 + h) * 8192 + t * 16);
    }
  };

  auto computeTile = [&](const unsigned short* kb, const unsigned short* vb) {
    // S^T = K · Q^T  (two 32x32 j-tiles)
    f32x16 st0, st1;
    #pragma unroll
    for (int r = 0; r < 16; ++r) { st0[r] = 0.f; st1[r] = 0.f; }
    __builtin_amdgcn_s_setprio(1);
    {
      int j = lo5;
      #pragma unroll
      for (int s = 0; s < 4; ++s) {
        short8 kf = *(const short8*)((const char*)kb + j * 128 +
                                     ((s * 32 + hi * 16) ^ ((j & 7) << 4)));
        st0 = MFMA32(kf, (s == 0 ? qf0 : s == 1 ? qf1 : s == 2 ? qf2 : qf3), st0, 0, 0, 0);
      }
    }
    {
      int j = 32 + lo5;
      #pragma unroll
      for (int s = 0; s < 4; ++s) {
        short8 kf = *(const short8*)((const char*)kb + j * 128 +
                                     ((s * 32 + hi * 16) ^ ((j & 7) << 4)));
        st1 = MFMA32(kf, (s == 0 ? qf0 : s == 1 ? qf1 : s == 2 ? qf2 : qf3), st1, 0, 0, 0);
      }
    }
    __builtin_amdgcn_s_setprio(0);

    // static-shift softmax: pure per-lane, no cross-lane ops, no rescale
    float ps0 = 0.f, ps1 = 0.f, ps2 = 0.f, ps3 = 0.f;
    #pragma unroll
    for (int r = 0; r < 16; ++r) {
      float p = exp2f(st0[r] * cE - mnc);
      st0[r] = p;
      if ((r & 3) == 0) ps0 += p; else if ((r & 3) == 1) ps1 += p;
      else if ((r & 3) == 2) ps2 += p; else ps3 += p;
    }
    #pragma unroll
    for (int r = 0; r < 16; ++r) {
      float p = exp2f(st1[r] * cE - mnc);
      st1[r] = p;
      if ((r & 3) == 0) ps0 += p; else if ((r & 3) == 1) ps1 += p;
      else if ((r & 3) == 2) ps2 += p; else ps3 += p;
    }
    l_run += (ps0 + ps1) + (ps2 + ps3);

    // repack P -> bf16 B-operand fragments (cvt_pk + permlane32_swap)
    unsigned int c0 = cvt_pk_bf16(st0[0], st0[1]);
    unsigned int c1 = cvt_pk_bf16(st0[2], st0[3]);
    unsigned int c2 = cvt_pk_bf16(st0[4], st0[5]);
    unsigned int c3 = cvt_pk_bf16(st0[6], st0[7]);
    unsigned int c4 = cvt_pk_bf16(st0[8], st0[9]);
    unsigned int c5 = cvt_pk_bf16(st0[10], st0[11]);
    unsigned int c6 = cvt_pk_bf16(st0[12], st0[13]);
    unsigned int c7 = cvt_pk_bf16(st0[14], st0[15]);
    pl32_swap(c0, c2); pl32_swap(c1, c3);
    pl32_swap(c4, c6); pl32_swap(c5, c7);
    u32x4 u0 = {c0, c1, c2, c3}, u1 = {c4, c5, c6, c7};
    short8 pf0 = __builtin_bit_cast(short8, u0);
    short8 pf1 = __builtin_bit_cast(short8, u1);
    c0 = cvt_pk_bf16(st1[0], st1[1]);
    c1 = cvt_pk_bf16(st1[2], st1[3]);
    c2 = cvt_pk_bf16(st1[4], st1[5]);
    c3 = cvt_pk_bf16(st1[6], st1[7]);
    c4 = cvt_pk_bf16(st1[8], st1[9]);
    c5 = cvt_pk_bf16(st1[10], st1[11]);
    c6 = cvt_pk_bf16(st1[12], st1[13]);
    c7 = cvt_pk_bf16(st1[14], st1[15]);
    pl32_swap(c0, c2); pl32_swap(c1, c3);
    pl32_swap(c4, c6); pl32_swap(c5, c7);
    u32x4 u2 = {c0, c1, c2, c3}, u3 = {c4, c5, c6, c7};
    short8 pf2 = __builtin_bit_cast(short8, u2);
    short8 pf3 = __builtin_bit_cast(short8, u3);

    // O^T += V^T · P^T  (two 32-d tiles)
    __builtin_amdgcn_s_setprio(1);
    {
      int d = lo5;
      #pragma unroll
      for (int s = 0; s < 4; ++s) {
        short8 vf = *(const short8*)((const char*)vb + d * 128 +
                                     ((s * 32 + hi * 16) ^ ((d & 7) << 4)));
        oacc0 = MFMA32(vf, (s == 0 ? pf0 : s == 1 ? pf1 : s == 2 ? pf2 : pf3), oacc0, 0, 0, 0);
      }
    }
    {
      int d = 32 + lo5;
      #pragma unroll
      for (int s = 0; s < 4; ++s) {
        short8 vf = *(const short8*)((const char*)vb + d * 128 +
                                     ((s * 32 + hi * 16) ^ ((d & 7) << 4)));
        oacc1 = MFMA32(vf, (s == 0 ? pf0 : s == 1 ? pf1 : s == 2 ? pf2 : pf3), oacc1, 0, 0, 0);
      }
    }
    __builtin_amdgcn_s_setprio(0);
  };

  auto kbuf = [&](int buf) {
    return (const unsigned short*)(smem + (buf * 2 + kvhalf) * 8192);
  };
  auto vbuf = [&](int buf) {
    return (const unsigned short*)(smem + 32768 + (buf * 2 + kvhalf) * 8192);
  };

  stage(0, 0);
  __syncthreads();
  for (int jt = 0; jt < 32; jt += 2) {
    stage(1, jt + 1);
    computeTile(kbuf(0), vbuf(0));
    __syncthreads();
    if (jt + 2 < 32) stage(0, jt + 2);
    computeTile(kbuf(1), vbuf(1));
    __syncthreads();
  }

  // combine lane<->lane^32 l once (only cross-lane op in the kernel)
  float l_tot = l_run + __shfl_xor(l_run, 32);

  // merge the two kv-half states (per q-group pair: wave qg <-> wave qg+4)
  float* scratch = (float*)smem;
  float* obase = scratch + qg * 2112;  // 8 chunks*256 + 64 l floats
  if (kvhalf == 1) {
    #pragma unroll
    for (int c = 0; c < 4; ++c) {
      f32x4 v = {oacc0[4 * c], oacc0[4 * c + 1], oacc0[4 * c + 2], oacc0[4 * c + 3]};
      *(f32x4*)(obase + c * 256 + lane * 4) = v;
    }
    #pragma unroll
    for (int c = 0; c < 4; ++c) {
      f32x4 v = {oacc1[4 * c], oacc1[4 * c + 1], oacc1[4 * c + 2], oacc1[4 * c + 3]};
      *(f32x4*)(obase + 1024 + c * 256 + lane * 4) = v;
    }
    obase[2048 + lane] = l_tot;
  }
  __syncthreads();
  if (kvhalf == 0) {
    float l_b = obase[2048 + lane];
    float linv = 1.f / (l_tot + l_b);
    float ob0[16], ob1[16];
    #pragma unroll
    for (int c = 0; c < 4; ++c) {
      f32x4 v = *(const f32x4*)(obase + c * 256 + lane * 4);
      #pragma unroll
      for (int e = 0; e < 4; ++e) ob0[4 * c + e] = v[e];
    }
    #pragma unroll
    for (int c = 0; c < 4; ++c) {
      f32x4 v = *(const f32x4*)(obase + 1024 + c * 256 + lane * 4);
      #pragma unroll
      for (int e = 0; e < 4; ++e) ob1[4 * c + e] = v[e];
    }
    unsigned short* oh = o + (size_t)bh * (4096 * 64);
    #pragma unroll
    for (int i = 0; i < 8; ++i) {
      float a0 = (oacc0[2 * i] + ob0[2 * i]) * linv;
      float a1 = (oacc0[2 * i + 1] + ob0[2 * i + 1]) * linv;
      float b0 = (oacc1[2 * i] + ob1[2 * i]) * linv;
      float b1 = (oacc1[2 * i + 1] + ob1[2 * i + 1]) * linv;
      unsigned int pk0 = cvt_pk_bf16(a0, a1);
      unsigned int pk1 = cvt_pk_bf16(b0, b1);
      int dl = ((2 * i) & 3) + 8 * ((2 * i) >> 2) + 4 * hi;
      *(unsigned int*)(oh + qrow * 64 + dl) = pk0;
      *(unsigned int*)(oh + qrow * 64 + 32 + dl) = pk1;
    }
  }
}

// ---------------------------------------------------------------------------
// GEMM2: out[b*n,512] (fp32) = o[(b,h,n,d)] @ w_out[512,512] + b_out
// ---------------------------------------------------------------------------
__global__ __launch_bounds__(256) void san_out(const unsigned short* __restrict__ o,
                                               const float* __restrict__ wo,
                                               const float* __restrict__ bias,
                                               float* __restrict__ out) {
  __shared__ unsigned short Alds[128 * 40];
  __shared__ unsigned short Blds[64 * 40];
  const int t = threadIdx.x;
  const int m0 = (blockIdx.x >> 3) * 128;
  const int n0 = (blockIdx.x & 7) * 64;
  const int lane = t & 63, wv = t >> 6;
  const int wr = wv >> 1, wc = wv & 1;
  const int lr = lane & 15, lg = lane >> 4;

  f32x4 acc[4][2];
  #pragma unroll
  for (int m = 0; m < 4; ++m)
    #pragma unroll
    for (int n = 0; n < 2; ++n) acc[m][n] = (f32x4){0.f, 0.f, 0.f, 0.f};

  for (int k0 = 0; k0 < 512; k0 += 32) {
    __syncthreads();
    {
      const int row = t >> 1, seg = t & 1;
      int grow = m0 + row;
      int b = grow >> 12, nn = grow & 4095;
      int h = k0 >> 6;
      int dbase = (k0 & 63) + seg * 16;
      const unsigned short* src =
          o + ((size_t)((b << 3) + h) * 4096 + nn) * 64 + dbase;
      *(u16x8*)&Alds[row * 40 + seg * 16]     = *(const u16x8*)src;
      *(u16x8*)&Alds[row * 40 + seg * 16 + 8] = *(const u16x8*)(src + 8);
    }
    {
      const int k = t & 31, nb = (t >> 5) * 8;
      const float* src = wo + (k0 + k) * 512 + n0 + nb;
      #pragma unroll
      for (int i = 0; i < 8; i += 4) {
        f32x4 v = *(const f32x4*)(src + i);
        #pragma unroll
        for (int e = 0; e < 4; ++e) Blds[(nb + i + e) * 40 + k] = f2bf(v[e]);
      }
    }
    __syncthreads();
    short8 af[4], bfr[2];
    #pragma unroll
    for (int m = 0; m < 4; ++m)
      af[m] = *(const short8*)&Alds[(wr * 64 + m * 16 + lr) * 40 + lg * 8];
    #pragma unroll
    for (int n = 0; n < 2; ++n)
      bfr[n] = *(const short8*)&Blds[(wc * 32 + n * 16 + lr) * 40 + lg * 8];
    #pragma unroll
    for (int m = 0; m < 4; ++m)
      #pragma unroll
      for (int n = 0; n < 2; ++n)
        acc[m][n] = MFMA16(af[m], bfr[n], acc[m][n], 0, 0, 0);
  }
  #pragma unroll
  for (int m = 0; m < 4; ++m)
    #pragma unroll
    for (int n = 0; n < 2; ++n)
      #pragma unroll
      for (int r = 0; r < 4; ++r) {
        int grow = m0 + wr * 64 + m * 16 + lg * 4 + r;
        int gcol = n0 + wc * 32 + n * 16 + lr;
        out[(size_t)grow * 512 + gcol] = acc[m][n][r] + bias[gcol];
      }
}

extern "C" void kernel_launch(void* const* d_in, const int* in_sizes, int n_in,
                              void* d_out, int out_size, void* d_ws, size_t ws_size,
                              hipStream_t stream) {
  const float* x    = (const float*)d_in[0];
  const float* wqkv = (const float*)d_in[1];
  const float* wo   = (const float*)d_in[2];
  const float* bias = (const float*)d_in[3];
  float* out = (float*)d_out;

  unsigned short* wsw = (unsigned short*)d_ws;             // 8 MB bf16 w
  unsigned short* wso = wsw + (size_t)2 * 8 * 4096 * 64;   // 8 MB bf16 o
  unsigned short* wst = (unsigned short*)d_out;            // wT parked in d_out

  san_qkv<<<dim3(512), dim3(256), 0, stream>>>(x, wqkv, wsw, wst);
  san_attn<<<dim3(512), dim3(512), 0, stream>>>(wsw, wst, wso);
  san_out<<<dim3(512), dim3(256), 0, stream>>>(wso, wo, bias, out);
}